// Round 7
// baseline (231.083 us; speedup 1.0000x reference)
//
#include <hip/hip_runtime.h>
#include <hip/hip_bf16.h>

// Problem constants (B=4, N=2048, C=768, H=12, D=64)
#define BB 4
#define NN 2048
#define CC 768
#define HH 12
#define DD 64

typedef __bf16 bf16;
typedef __attribute__((ext_vector_type(8))) __bf16 bf16x8;
typedef __attribute__((ext_vector_type(4))) __bf16 bf16x4;
typedef __attribute__((ext_vector_type(4))) float f32x4;

// ---- workspace layout (bf16 elems) ----------------------------------------
#define SZ_X    (BB * NN * CC)              // 6291456
#define SZ_QKVW (3 * CC * CC)               // 1769472
#define SZ_PW   (CC * CC)                   // 589824
#define SZ_QKV  ((size_t)BB * NN * 3 * CC)  // 18874368

#define OFF_X    0
#define OFF_QW   (OFF_X + SZ_X)
#define OFF_PW   (OFF_QW + SZ_QKVW)
#define OFF_QKV  (OFF_PW + SZ_PW)           // end = 27525120 elems = 55.1 MB
// Vt [B*H][D][N] (12.6 MB) lives in d_out (25.2 MB f32 scratch until proj).

// Direct-to-LDS 16B DMA; source chunk XOR-swizzled to kill read conflicts.
__device__ __forceinline__ void async16(const bf16* g, bf16* l) {
    __builtin_amdgcn_global_load_lds(
        (const __attribute__((address_space(1))) unsigned int*)g,
        (__attribute__((address_space(3))) unsigned int*)l, 16, 0, 0);
}

// ---------------------------------------------------------------------------
// Vectorized f32 -> bf16 casts: 8 elems/thread (2x f32x4 load, 1x bf16x8 store).
// ---------------------------------------------------------------------------
__device__ __forceinline__ void cast8(const float* __restrict__ src,
                                      bf16* __restrict__ dst, int i) {
    f32x4 a = ((const f32x4*)src)[2 * i];
    f32x4 b = ((const f32x4*)src)[2 * i + 1];
    bf16x8 o;
#pragma unroll
    for (int j = 0; j < 4; ++j) { o[j] = (bf16)a[j]; o[j + 4] = (bf16)b[j]; }
    ((bf16x8*)dst)[i] = o;
}

__global__ __launch_bounds__(256) void convert3(
    const float* __restrict__ x, const float* __restrict__ qkvw,
    const float* __restrict__ pw, bf16* __restrict__ ws) {
    const int t = blockIdx.x * 256 + threadIdx.x;
    const int S = gridDim.x * 256;
    for (int i = t; i < SZ_X / 8;    i += S) cast8(x,    ws + OFF_X,  i);
    for (int i = t; i < SZ_QKVW / 8; i += S) cast8(qkvw, ws + OFF_QW, i);
    for (int i = t; i < SZ_PW / 8;   i += S) cast8(pw,   ws + OFF_PW, i);
}

// ---------------------------------------------------------------------------
// QKV GEMM with fused RMSNorm+RoPE epilogue + direct-transposed V store
// (verified rounds 4-5, unchanged).
// ---------------------------------------------------------------------------
__global__ __launch_bounds__(256) void gemm_qkv(
    const bf16* __restrict__ A, const bf16* __restrict__ W,
    bf16* __restrict__ C, bf16* __restrict__ Vt,
    const float* __restrict__ cosb, const float* __restrict__ sinb,
    const float* __restrict__ qw, const float* __restrict__ kw) {
    __shared__ __align__(16) bf16 As[128 * 64];
    __shared__ __align__(16) bf16 Bs[128 * 64];
    const int tid  = threadIdx.x;
    const int wave = tid >> 6;
    const int lane = tid & 63;
    const int quad = lane >> 4;
    const int l16  = lane & 15;
    const int m0 = blockIdx.y * 128;
    const int n0 = blockIdx.x * 128;
    const int wm = (wave >> 1) * 64;
    const int wn = (wave & 1) * 64;
    const int srow = lane >> 3;
    const int swz  = (lane & 7) ^ srow;
    const int K = CC;
    const int Nn = 3 * CC;

    f32x4 acc[4][4];
#pragma unroll
    for (int i = 0; i < 4; ++i)
#pragma unroll
        for (int j = 0; j < 4; ++j) acc[i][j] = (f32x4){0.f, 0.f, 0.f, 0.f};

    for (int k0 = 0; k0 < K; k0 += 64) {
#pragma unroll
        for (int i = 0; i < 4; ++i) {
            int row = i * 32 + wave * 8 + srow;
            async16(A + (size_t)(m0 + row) * CC + k0 + swz * 8,
                    &As[(i * 32 + wave * 8) * 64]);
            async16(W + (size_t)(n0 + row) * K + k0 + swz * 8,
                    &Bs[(i * 32 + wave * 8) * 64]);
        }
        __syncthreads();
#pragma unroll
        for (int kk = 0; kk < 2; ++kk) {
            const int slot = ((kk * 4 + quad) ^ (l16 & 7)) * 8;
            bf16x8 af[4], bf[4];
#pragma unroll
            for (int mt = 0; mt < 4; ++mt)
                af[mt] = *(const bf16x8*)(&As[(wm + mt * 16 + l16) * 64 + slot]);
#pragma unroll
            for (int nt = 0; nt < 4; ++nt)
                bf[nt] = *(const bf16x8*)(&Bs[(wn + nt * 16 + l16) * 64 + slot]);
#pragma unroll
            for (int mt = 0; mt < 4; ++mt)
#pragma unroll
                for (int nt = 0; nt < 4; ++nt)
                    acc[mt][nt] = __builtin_amdgcn_mfma_f32_16x16x32_bf16(
                        af[mt], bf[nt], acc[mt][nt], 0, 0, 0);
        }
        __syncthreads();
    }

    const int colblk = n0 + wn;          // 64-aligned; one head of q/k/v
    const int sector = colblk / CC;      // 0=q, 1=k, 2=v
    if (sector == 2) {
        // v: transposed store straight to Vt[bh][d][n]; no qkv store.
        const int head = (colblk >> 6) - 24;     // (colblk - 2*CC)/64
        const int btok = m0 + wm;                // first token row of this wave
        const int bh   = (btok >> 11) * HH + head;
        const int nloc = btok & (NN - 1);
#pragma unroll
        for (int nt = 0; nt < 4; ++nt) {
            const int d = nt * 16 + l16;
            bf16* dst = Vt + ((size_t)bh * DD + d) * NN + nloc + quad * 4;
#pragma unroll
            for (int mt = 0; mt < 4; ++mt) {
                bf16x4 pk;
#pragma unroll
                for (int r = 0; r < 4; ++r) pk[r] = (bf16)acc[mt][nt][r];
                *(bf16x4*)(dst + mt * 16) = pk;
            }
        }
    } else {
        const float* wp = (sector == 0) ? qw : kw;
        const float qs = (sector == 0) ? 0.18033688f : 1.0f;  // CEXP fold
        float wv[4];
#pragma unroll
        for (int nt = 0; nt < 4; ++nt) wv[nt] = wp[nt * 16 + l16];
#pragma unroll
        for (int mt = 0; mt < 4; ++mt)
#pragma unroll
            for (int r = 0; r < 4; ++r) {
                const int row = m0 + wm + mt * 16 + quad * 4 + r;
                const int n   = row & (NN - 1);
                float v[4];
#pragma unroll
                for (int nt = 0; nt < 4; ++nt) v[nt] = acc[mt][nt][r];
                float ss = v[0] * v[0] + v[1] * v[1] + v[2] * v[2] + v[3] * v[3];
                ss += __shfl_xor(ss, 1, 64);
                ss += __shfl_xor(ss, 2, 64);
                ss += __shfl_xor(ss, 4, 64);
                ss += __shfl_xor(ss, 8, 64);
                const float rn = rsqrtf(ss * (1.0f / 64.0f) + 1e-6f);
#pragma unroll
                for (int nt = 0; nt < 4; ++nt) v[nt] *= rn * wv[nt];
                // RoPE: d = nt*16+l16; partner d+-32 = reg nt^2; j = d&31
                const float c0 = cosb[n * 32 + l16];
                const float c1 = cosb[n * 32 + 16 + l16];
                const float s0 = sinb[n * 32 + l16];
                const float s1 = sinb[n * 32 + 16 + l16];
                float y[4];
                y[0] = v[0] * c0 - v[2] * s0;
                y[1] = v[1] * c1 - v[3] * s1;
                y[2] = v[2] * c0 + v[0] * s0;
                y[3] = v[3] * c1 + v[1] * s1;
#pragma unroll
                for (int nt = 0; nt < 4; ++nt) {
                    int col = colblk + nt * 16 + l16;
                    C[(size_t)row * Nn + col] = (bf16)(y[nt] * qs);
                }
            }
    }
}

// ---------------------------------------------------------------------------
// Output projection GEMM, 128x64 tiles, grid = 768 = 3 blocks/CU (verified
// round 5, unchanged).
// ---------------------------------------------------------------------------
__global__ __launch_bounds__(256) void gemm_proj(
    const bf16* __restrict__ A, const bf16* __restrict__ W,
    const float* __restrict__ bias, float* __restrict__ C) {
    __shared__ __align__(16) bf16 As[128 * 64];
    __shared__ __align__(16) bf16 Bs[64 * 64];
    const int tid  = threadIdx.x;
    const int wave = tid >> 6;
    const int lane = tid & 63;
    const int quad = lane >> 4;
    const int l16  = lane & 15;
    const int m0 = blockIdx.y * 128;
    const int n0 = blockIdx.x * 64;
    const int wm = (wave >> 1) * 64;
    const int wn = (wave & 1) * 32;
    const int srow = lane >> 3;
    const int swz  = (lane & 7) ^ srow;
    const int lda = 3 * CC;                 // A = v-slice of qkv
    const int K = CC;

    f32x4 acc[4][2];
#pragma unroll
    for (int i = 0; i < 4; ++i)
#pragma unroll
        for (int j = 0; j < 2; ++j) acc[i][j] = (f32x4){0.f, 0.f, 0.f, 0.f};

    for (int k0 = 0; k0 < K; k0 += 64) {
#pragma unroll
        for (int i = 0; i < 4; ++i) {
            int row = i * 32 + wave * 8 + srow;
            async16(A + (size_t)(m0 + row) * lda + k0 + swz * 8,
                    &As[(i * 32 + wave * 8) * 64]);
        }
#pragma unroll
        for (int i = 0; i < 2; ++i) {
            int row = i * 32 + wave * 8 + srow;
            async16(W + (size_t)(n0 + row) * K + k0 + swz * 8,
                    &Bs[(i * 32 + wave * 8) * 64]);
        }
        __syncthreads();
#pragma unroll
        for (int kk = 0; kk < 2; ++kk) {
            const int slot = ((kk * 4 + quad) ^ (l16 & 7)) * 8;
            bf16x8 af[4], bf[2];
#pragma unroll
            for (int mt = 0; mt < 4; ++mt)
                af[mt] = *(const bf16x8*)(&As[(wm + mt * 16 + l16) * 64 + slot]);
#pragma unroll
            for (int nt = 0; nt < 2; ++nt)
                bf[nt] = *(const bf16x8*)(&Bs[(wn + nt * 16 + l16) * 64 + slot]);
#pragma unroll
            for (int mt = 0; mt < 4; ++mt)
#pragma unroll
                for (int nt = 0; nt < 2; ++nt)
                    acc[mt][nt] = __builtin_amdgcn_mfma_f32_16x16x32_bf16(
                        af[mt], bf[nt], acc[mt][nt], 0, 0, 0);
        }
        __syncthreads();
    }
#pragma unroll
    for (int mt = 0; mt < 4; ++mt)
#pragma unroll
        for (int nt = 0; nt < 2; ++nt)
#pragma unroll
            for (int r = 0; r < 4; ++r) {
                int row = m0 + wm + mt * 16 + quad * 4 + r;
                int col = n0 + wn + nt * 16 + l16;
                C[(size_t)row * CC + col] = acc[mt][nt][r] + bias[col];
            }
}

// ---------------------------------------------------------------------------
// Flash attention, round-7: kt-split wave pairs.
// DS-traffic model (round-6 post-mortem): 8 waves x 16q read K+V 8x per tile
// -> 160 KB/tile -> 3.93 GB total = 75 us at 85 B/cyc/CU ds_read_b128 rate =
// measured 74.2.  Fix: 8 waves x 32q, waves 0-3 on EVEN K-tiles, 4-7 on ODD
// (same 128 q-rows), 2 tiles staged per step -> each wave reads K/V once per
// its tile: 96 KB/tile (-40%).  Exp2-domain softmax (no running max) makes
// partials linearly combinable: epilogue sums accO/lsum of wave pairs via
// LDS (dead Ps region as f32 scratch) then normalizes.  LDS 68 KB -> 2
// blocks/CU = 16 waves/CU (round-6's occupancy, round-5's traffic).
// ---------------------------------------------------------------------------
__global__ __launch_bounds__(512) void flash_attn(
    const bf16* __restrict__ qkv, const bf16* __restrict__ Vt,
    bf16* __restrict__ Oqkv) {
    __shared__ __align__(16) bf16 Ks[2][64 * 64];    // [tile][key][d] swizzled
    __shared__ __align__(16) bf16 Vs[2][64 * 64];    // [tile][d][key] swizzled
    __shared__ __align__(16) bf16 Ps[8][32 * 72];    // per-wave [q][key], padded
    const int tid  = threadIdx.x;
    const int wave = tid >> 6;          // 0..7
    const int w4   = wave & 3;          // q-group (32 rows)
    const int half = wave >> 2;         // kt parity this wave computes
    const int lane = tid & 63;
    const int quad = lane >> 4;
    const int l16  = lane & 15;
    const int r7   = l16 & 7;
    const int bh = blockIdx.x;
    const int qt = blockIdx.y;
    const int b = bh / HH, h = bh % HH;
    const size_t rs = 3 * CC;
    const bf16* Qb  = qkv + (size_t)b * NN * rs + h * DD;
    const bf16* Kb  = Qb + CC;
    const bf16* Vtb = Vt + (size_t)bh * DD * NN;

    bf16x8 qf[2][2];
#pragma unroll
    for (int f = 0; f < 2; ++f) {
        const int qrow = qt * 128 + w4 * 32 + f * 16 + l16;
#pragma unroll
        for (int hf = 0; hf < 2; ++hf)
            qf[f][hf] = *(const bf16x8*)(Qb + (size_t)qrow * rs + hf * 32 + quad * 8);
    }

    f32x4 accO[2][4];
#pragma unroll
    for (int f = 0; f < 2; ++f)
#pragma unroll
        for (int i = 0; i < 4; ++i) accO[f][i] = (f32x4){0.f, 0.f, 0.f, 0.f};
    float lsum[2] = {0.f, 0.f};

    const int srow  = lane >> 3;
    const int swz   = (lane & 7) ^ srow;
    const int strow = wave * 8 + srow;      // staging rows: 8 per wave

    for (int step = 0; step < NN / 128; ++step) {
        const int t0 = step * 2;
        // stage BOTH tiles of the pair (4 DMA issues per wave, 8 rows each)
        async16(Kb + (size_t)(t0 * 64 + strow) * rs + swz * 8,
                &Ks[0][(wave * 8) * 64]);
        async16(Kb + (size_t)((t0 + 1) * 64 + strow) * rs + swz * 8,
                &Ks[1][(wave * 8) * 64]);
        async16(Vtb + (size_t)strow * NN + t0 * 64 + swz * 8,
                &Vs[0][(wave * 8) * 64]);
        async16(Vtb + (size_t)strow * NN + (t0 + 1) * 64 + swz * 8,
                &Vs[1][(wave * 8) * 64]);
        __syncthreads();

        const bf16* Kc = Ks[half];
        const bf16* Vc = Vs[half];

        // S^T = (Q K^T)^T via swapped operands; scores already exp2-domain
        f32x4 s[2][4];
#pragma unroll
        for (int nt = 0; nt < 4; ++nt) {
            const int row = nt * 16 + l16;
            bf16x8 kf0 = *(const bf16x8*)(&Kc[row * 64 + (quad ^ r7) * 8]);
            bf16x8 kf1 = *(const bf16x8*)(&Kc[row * 64 + ((quad + 4) ^ r7) * 8]);
#pragma unroll
            for (int f = 0; f < 2; ++f) {
                f32x4 z = (f32x4){0.f, 0.f, 0.f, 0.f};
                z = __builtin_amdgcn_mfma_f32_16x16x32_bf16(kf0, qf[f][0], z, 0, 0, 0);
                s[f][nt] = __builtin_amdgcn_mfma_f32_16x16x32_bf16(kf1, qf[f][1], z, 0, 0, 0);
            }
        }

        // p = exp2(s); packed b64 stores (4 consecutive keys per store)
#pragma unroll
        for (int f = 0; f < 2; ++f)
#pragma unroll
            for (int nt = 0; nt < 4; ++nt) {
                bf16x4 pk;
#pragma unroll
                for (int r = 0; r < 4; ++r) {
                    float pv = __builtin_amdgcn_exp2f(s[f][nt][r]);
                    lsum[f] += pv;
                    pk[r] = (bf16)pv;
                }
                *(bf16x4*)(&Ps[wave][(f * 16 + l16) * 72 + nt * 16 + quad * 4]) = pk;
            }
        // Ps wave-private: wave-local DS drain + compiler fence
        __asm__ volatile("s_waitcnt lgkmcnt(0)" ::: "memory");

        bf16x8 pf0[2], pf1[2];
#pragma unroll
        for (int f = 0; f < 2; ++f) {
            pf0[f] = *(const bf16x8*)(&Ps[wave][(f * 16 + l16) * 72 + quad * 8]);
            pf1[f] = *(const bf16x8*)(&Ps[wave][(f * 16 + l16) * 72 + 32 + quad * 8]);
        }
#pragma unroll
        for (int nt = 0; nt < 4; ++nt) {
            const int rowd = nt * 16 + l16;
            bf16x8 vf0 = *(const bf16x8*)(&Vc[rowd * 64 + (quad ^ r7) * 8]);
            bf16x8 vf1 = *(const bf16x8*)(&Vc[rowd * 64 + ((quad + 4) ^ r7) * 8]);
#pragma unroll
            for (int f = 0; f < 2; ++f) {
                accO[f][nt] = __builtin_amdgcn_mfma_f32_16x16x32_bf16(pf0[f], vf0, accO[f][nt], 0, 0, 0);
                accO[f][nt] = __builtin_amdgcn_mfma_f32_16x16x32_bf16(pf1[f], vf1, accO[f][nt], 0, 0, 0);
            }
        }
        __syncthreads();   // all waves done reading Ks/Vs/Ps before restage
    }

    // lsum: reduce over the 4 quads sharing l16 (lane's q = f*16+l16)
#pragma unroll
    for (int f = 0; f < 2; ++f) {
        lsum[f] += __shfl_xor(lsum[f], 16, 64);
        lsum[f] += __shfl_xor(lsum[f], 32, 64);
    }

    // ---- combine kt-halves: waves w and w+4 hold partials for the same q.
    // Ps region is dead (trailing loop barrier covers all reads) -> f32 scratch.
    float* Osc = (float*)&Ps[0][0];          // [4][32][65] f32 (pad 65 vs banks)
    float* Ls  = Osc + 4 * 32 * 65;          // [4][32] f32
    if (wave >= 4) {
#pragma unroll
        for (int f = 0; f < 2; ++f) {
            if (quad == 0) Ls[w4 * 32 + f * 16 + l16] = lsum[f];
#pragma unroll
            for (int nt = 0; nt < 4; ++nt)
#pragma unroll
                for (int r = 0; r < 4; ++r)
                    Osc[(w4 * 32 + f * 16 + quad * 4 + r) * 65 + nt * 16 + l16] =
                        accO[f][nt][r];
        }
    }
    __syncthreads();
    if (wave < 4) {
#pragma unroll
        for (int f = 0; f < 2; ++f) {
            lsum[f] += Ls[w4 * 32 + f * 16 + l16];
#pragma unroll
            for (int nt = 0; nt < 4; ++nt)
#pragma unroll
                for (int r = 0; r < 4; ++r)
                    accO[f][nt][r] +=
                        Osc[(w4 * 32 + f * 16 + quad * 4 + r) * 65 + nt * 16 + l16];
        }
        // epilogue: accO row q = f*16+quad*4+r; 1/lsum from lane quad*4+r
#pragma unroll
        for (int f = 0; f < 2; ++f)
#pragma unroll
            for (int r = 0; r < 4; ++r) {
                float inv = 1.0f / __shfl(lsum[f], quad * 4 + r, 64);
                int n = qt * 128 + w4 * 32 + f * 16 + quad * 4 + r;
#pragma unroll
                for (int nt = 0; nt < 4; ++nt) {
                    int col = h * DD + nt * 16 + l16;
                    Oqkv[(size_t)(b * NN + n) * rs + 2 * CC + col] =
                        (bf16)(accO[f][nt][r] * inv);
                }
            }
    }
}

// ---------------------------------------------------------------------------
extern "C" void kernel_launch(void* const* d_in, const int* in_sizes, int n_in,
                              void* d_out, int out_size, void* d_ws, size_t ws_size,
                              hipStream_t stream) {
    const float* x     = (const float*)d_in[0];
    const float* cosb  = (const float*)d_in[1];
    const float* sinb  = (const float*)d_in[2];
    const float* qkv_w = (const float*)d_in[3];
    const float* qnw   = (const float*)d_in[4];
    const float* knw   = (const float*)d_in[5];
    const float* pw    = (const float*)d_in[6];
    const float* pb    = (const float*)d_in[7];
    float* out = (float*)d_out;

    bf16* ws  = (bf16*)d_ws;
    bf16* xb  = ws + OFF_X;
    bf16* qwb = ws + OFF_QW;
    bf16* pwb = ws + OFF_PW;
    bf16* qkv = ws + OFF_QKV;
    bf16* vt  = (bf16*)d_out;   // scratch: Vt [B*H][D][N] = 12.6 MB of the
                                // 25.2 MB out buffer; proj overwrites it last.

    const int M = BB * NN;  // 8192

    // 0) cast MFMA operands to bf16 (vectorized 8/thread)
    convert3<<<1024, 256, 0, stream>>>(x, qkv_w, pw, ws);

    // 1) QKV projection + fused RMSNorm/RoPE/CEXP; v-sector written
    //    transposed straight to Vt
    dim3 g1(3 * CC / 128, M / 128);
    gemm_qkv<<<g1, 256, 0, stream>>>(xb, qwb, qkv, vt, cosb, sinb, qnw, knw);

    // 2) Flash attention -> v-slice of qkv; 128 q-rows, kt-split wave pairs
    dim3 g4(BB * HH, NN / 128);
    flash_attn<<<g4, 512, 0, stream>>>(qkv, vt, qkv);

    // 3) Output projection (+fp32 bias) -> d_out; 128x64 tiles, 3 blocks/CU
    dim3 g5(CC / 64, M / 128);
    gemm_proj<<<g5, 256, 0, stream>>>(qkv + 2 * CC, pwb, pb, out);
}